// Round 9
// baseline (347.857 us; speedup 1.0000x reference)
//
#include <hip/hip_runtime.h>

#define T_SEQ  2048
#define TK_SEQ 2049
#define JP     2080                       // padded key length (zeroed pads)
#define SL_F    0.12751744f               // SCALE * log2(e)
#define THR_L2  11.0f                     // defer-max threshold (log2 domain)

typedef __attribute__((ext_vector_type(8))) short short8;
typedef __attribute__((ext_vector_type(4))) float f32x4;

__device__ __forceinline__ unsigned short f2bf(float f) {
  unsigned int u = __float_as_uint(f);
  u += 0x7fff + ((u >> 16) & 1);          // round-to-nearest-even
  return (unsigned short)(u >> 16);
}

// async global->LDS 16B copy: LDS dest = wave-uniform base + lane*16
__device__ __forceinline__ void gload16(const unsigned short* g, unsigned short* l) {
  __builtin_amdgcn_global_load_lds(
      (const __attribute__((address_space(1))) void*)g,
      (__attribute__((address_space(3))) void*)l, 16, 0, 0);
}

// ---------------------------------------------------------------------------
// split_pack: f32 -> PLANE-SEPARATED split: bf16 hi (trunc) plane at d[0..],
// bf16 lo (RNE residual) plane at d[plane..].  Two ranges per launch.
// ---------------------------------------------------------------------------
__global__ __launch_bounds__(256) void split_pack(const float4* __restrict__ s0,
                                                  unsigned short* __restrict__ d0,
                                                  int n0, int p0,
                                                  const float4* __restrict__ s1,
                                                  unsigned short* __restrict__ d1,
                                                  int n1, int p1) {
  int i = blockIdx.x * 256 + threadIdx.x;
  const float4* s; unsigned short* d; int k, p;
  if (i < n0) { s = s0; d = d0; k = i; p = p0; }
  else { k = i - n0; if (k >= n1) return; s = s1; d = d1; p = p1; }
  float4 f = s[k];
  float fv[4] = {f.x, f.y, f.z, f.w};
  ushort4 hv, lv;
#pragma unroll
  for (int e = 0; e < 4; ++e) {
    unsigned int u = __float_as_uint(fv[e]) & 0xffff0000u;
    ((unsigned short*)&hv)[e] = (unsigned short)(u >> 16);
    ((unsigned short*)&lv)[e] = f2bf(fv[e] - __uint_as_float(u));
  }
  *(ushort4*)(d + 4 * (size_t)k)     = hv;
  *(ushort4*)(d + p + 4 * (size_t)k) = lv;
}

// ---------------------------------------------------------------------------
// Split-f32 MFMA GEMM, plane-split operands: C[M,N] = A[M,K] * B[N,K]^T.
// C ~= AhBh + AlBh + AhBl (f32 accum).  128x128 tile, 4 waves (2Mx2N), each
// wave 64x64 = 4x4 frags x 3 passes = 48 MFMA per K-step from 16 ds_read_b128
// (3.0 MFMA/read, was 2.0) -- LDS pipe was the measured critical path.
// BK=32, LDS double-buffer + global_load_lds DMA + counted s_waitcnt vmcnt(8)
// + raw s_barrier (loads stay in flight across the barrier).
// ---------------------------------------------------------------------------
__global__ __launch_bounds__(256, 2) void gemm_sp(const unsigned short* __restrict__ Ag,
                                                  const unsigned short* __restrict__ Bg,
                                                  float* __restrict__ C,
                                                  int M, int N, int K) {
  __shared__ unsigned short Ah[2][128 * 32], Al[2][128 * 32];
  __shared__ unsigned short Bh[2][128 * 32], Bl[2][128 * 32];

  const int tid  = threadIdx.x;
  const int lane = tid & 63;
  const int wid  = tid >> 6;
  const int wm   = (wid >> 1) << 6;       // 0 / 64
  const int wn   = (wid & 1) << 6;        // 0 / 64
  const int lo16 = lane & 15;
  const int hi4  = lane >> 4;
  const int m0   = blockIdx.y << 7;
  const int n0   = blockIdx.x << 7;
  const size_t MK = (size_t)M * K;        // lo-plane offset for A
  const size_t NK = (size_t)N * K;        // lo-plane offset for B

  // staging chunk map: chunk c -> row c>>2, col (c&3)*8 (16B per chunk)
  const int c0 = (wid << 6) + lane;             // chunks   0..255
  const int c1 = ((4 + wid) << 6) + lane;       // chunks 256..511
  const unsigned short* a0g = Ag + (size_t)(m0 + (c0 >> 2)) * K + ((c0 & 3) << 3);
  const unsigned short* a1g = Ag + (size_t)(m0 + (c1 >> 2)) * K + ((c1 & 3) << 3);
  const unsigned short* b0g = Bg + (size_t)(n0 + (c0 >> 2)) * K + ((c0 & 3) << 3);
  const unsigned short* b1g = Bg + (size_t)(n0 + (c1 >> 2)) * K + ((c1 & 3) << 3);
  const int o0 = wid << 9;                // wave-uniform LDS elem offsets
  const int o1 = (4 + wid) << 9;

  // fragment ds_read offsets (frag layout: row = lane&15, k = (lane>>4)*8+e)
  int ra[4], rb[4];
#pragma unroll
  for (int i = 0; i < 4; ++i) {
    ra[i] = ((wm + i * 16 + lo16) << 5) + (hi4 << 3);
    rb[i] = ((wn + i * 16 + lo16) << 5) + (hi4 << 3);
  }

  f32x4 acc[4][4];
  const f32x4 z4 = {0.f, 0.f, 0.f, 0.f};
#pragma unroll
  for (int i = 0; i < 4; ++i)
#pragma unroll
    for (int j = 0; j < 4; ++j) acc[i][j] = z4;

  // prologue: stage tile 0 into buffer 0 (8 DMA loads per wave)
  gload16(a0g,      &Ah[0][o0]);
  gload16(a1g,      &Ah[0][o1]);
  gload16(a0g + MK, &Al[0][o0]);
  gload16(a1g + MK, &Al[0][o1]);
  gload16(b0g,      &Bh[0][o0]);
  gload16(b1g,      &Bh[0][o1]);
  gload16(b0g + NK, &Bl[0][o0]);
  gload16(b1g + NK, &Bl[0][o1]);

  int cur = 0;
  for (int k0 = 0; k0 < K; k0 += 32) {
    const bool more = (k0 + 32) < K;
    if (more) {                           // issue next-tile DMA into other buf
      const int nxt = cur ^ 1;
      const int kn  = k0 + 32;
      gload16(a0g + kn,      &Ah[nxt][o0]);
      gload16(a1g + kn,      &Ah[nxt][o1]);
      gload16(a0g + MK + kn, &Al[nxt][o0]);
      gload16(a1g + MK + kn, &Al[nxt][o1]);
      gload16(b0g + kn,      &Bh[nxt][o0]);
      gload16(b1g + kn,      &Bh[nxt][o1]);
      gload16(b0g + NK + kn, &Bl[nxt][o0]);
      gload16(b1g + NK + kn, &Bl[nxt][o1]);
      asm volatile("s_waitcnt vmcnt(8)" ::: "memory");  // cur's 8 loads done
    } else {
      asm volatile("s_waitcnt vmcnt(0)" ::: "memory");
    }
    __builtin_amdgcn_s_barrier();         // all waves' cur-buffer DMA landed
    __builtin_amdgcn_sched_barrier(0);

    short8 fah[4], fal[4], fbh[4], fbl[4];
#pragma unroll
    for (int i = 0; i < 4; ++i) {
      fah[i] = *(const short8*)&Ah[cur][ra[i]];
      fal[i] = *(const short8*)&Al[cur][ra[i]];
      fbh[i] = *(const short8*)&Bh[cur][rb[i]];
      fbl[i] = *(const short8*)&Bl[cur][rb[i]];
    }
#pragma unroll
    for (int i = 0; i < 4; ++i)
#pragma unroll
      for (int j = 0; j < 4; ++j) {
        acc[i][j] = __builtin_amdgcn_mfma_f32_16x16x32_bf16(fah[i], fbh[j], acc[i][j], 0, 0, 0);
        acc[i][j] = __builtin_amdgcn_mfma_f32_16x16x32_bf16(fal[i], fbh[j], acc[i][j], 0, 0, 0);
        acc[i][j] = __builtin_amdgcn_mfma_f32_16x16x32_bf16(fah[i], fbl[j], acc[i][j], 0, 0, 0);
      }

    __builtin_amdgcn_sched_barrier(0);
    __builtin_amdgcn_s_barrier();         // all waves done READING cur buf
    asm volatile("" ::: "memory");
    cur ^= 1;
  }

  // epilogue: D col = lane&15, row = (lane>>4)*4 + reg
#pragma unroll
  for (int i = 0; i < 4; ++i) {
    const int row = m0 + wm + i * 16 + (hi4 << 2);
#pragma unroll
    for (int j = 0; j < 4; ++j) {
      float* cp = C + (size_t)row * N + n0 + wn + j * 16 + lo16;
      cp[0]            = acc[i][j][0];
      cp[(size_t)N]    = acc[i][j][1];
      cp[(size_t)2*N]  = acc[i][j][2];
      cp[(size_t)3*N]  = acc[i][j][3];
    }
  }
}

// ---------------------------------------------------------------------------
// rope2: RoPE + bf16 operand assembly, all sections coalesced.  (unchanged)
// ---------------------------------------------------------------------------
#define RB_Q  4096
#define RB_K  1024
#define RB_KE 64
#define RB_V  65

__global__ __launch_bounds__(256) void rope2(const float* __restrict__ qkv,
                                             const float* __restrict__ cosb,
                                             const float* __restrict__ sinb,
                                             const float* __restrict__ ksink,
                                             const float* __restrict__ vsink,
                                             unsigned short* __restrict__ qb,
                                             unsigned short* __restrict__ kb,
                                             unsigned short* __restrict__ vtb) {
  __shared__ unsigned short tl[512 * 33];
  const int bid = blockIdx.x, tid = threadIdx.x;
  if (bid < RB_Q) {
    int idx = bid * 256 + tid;            // 1,048,576: (t, h, dp/2)
    int t = idx >> 9, rem = idx & 511;
    int h = rem >> 5, dp = (rem & 31) << 1;
    int g = h >> 2, qi = h & 3;
    const float* src = qkv + (size_t)t * 3072 + g * 768 + qi * 128;
    float2 x1 = *(const float2*)(src + dp);
    float2 x2 = *(const float2*)(src + 64 + dp);
    float2 c  = *(const float2*)(cosb + t * 64 + dp);
    float2 s  = *(const float2*)(sinb + t * 64 + dp);
    ushort2 o1 = { f2bf(x1.x * c.x - x2.x * s.x), f2bf(x1.y * c.y - x2.y * s.y) };
    ushort2 o2 = { f2bf(x1.x * s.x + x2.x * c.x), f2bf(x1.y * s.y + x2.y * c.y) };
    *(ushort2*)(qb + (size_t)t * 2048 + h * 128 + dp)      = o1;
    *(ushort2*)(qb + (size_t)t * 2048 + h * 128 + 64 + dp) = o2;
  } else if (bid < RB_Q + RB_K) {
    int idx = (bid - RB_Q) * 256 + tid;   // 262,144: (t, g, dp/2)
    int t = idx >> 7, rem = idx & 127;
    int g = rem >> 5, dp = (rem & 31) << 1;
    const float* src = qkv + (size_t)t * 3072 + g * 768 + 512;
    float2 x1 = *(const float2*)(src + dp);
    float2 x2 = *(const float2*)(src + 64 + dp);
    float2 c  = *(const float2*)(cosb + t * 64 + dp);
    float2 s  = *(const float2*)(sinb + t * 64 + dp);
    ushort2 o1 = { f2bf(x1.x * c.x - x2.x * s.x), f2bf(x1.y * c.y - x2.y * s.y) };
    ushort2 o2 = { f2bf(x1.x * s.x + x2.x * c.x), f2bf(x1.y * s.y + x2.y * c.y) };
    size_t base = (size_t)(t + 1) * 512 + g * 128 + dp;
    *(ushort2*)(kb + base)      = o1;
    *(ushort2*)(kb + base + 64) = o2;
  } else if (bid < RB_Q + RB_K + RB_KE) {
    int idx = (bid - RB_Q - RB_K) * 256 + tid;   // 16,384: sink + pads
    int jj = idx >> 9, c = idx & 511;
    if (jj == 0) kb[c] = f2bf(ksink[c]);
    else         kb[(size_t)(2048 + jj) * 512 + c] = 0;
  } else {
    int b  = bid - RB_Q - RB_K - RB_KE;   // 0..64, j-tile of 32
    int j0 = b << 5;
#pragma unroll 4
    for (int st = 0; st < 64; ++st) {
      int id = st * 256 + tid;            // 16,384 = 32 j x 512 gd
      int jj = id >> 9, c = id & 511;
      int j = j0 + jj;
      float val;
      if (j == 0)          val = vsink[c];
      else if (j <= T_SEQ) val = qkv[(size_t)(j - 1) * 3072 + (c >> 7) * 768 + 640 + (c & 127)];
      else                 val = 0.f;
      tl[c * 33 + jj] = f2bf(val);
    }
    __syncthreads();
#pragma unroll 4
    for (int st = 0; st < 32; ++st) {
      int id = st * 256 + tid;            // 8,192 = 512 rows x 16 jp-pairs
      int row = id >> 4, jp = (id & 15) << 1;
      ushort2 w = { tl[row * 33 + jp], tl[row * 33 + jp + 1] };
      *(ushort2*)(vtb + (size_t)row * JP + j0 + jp) = w;
    }
  }
}

// ---------------------------------------------------------------------------
// MFMA flash attention with per-block LDS K/V staging (double-buffered).
// Blocks >= 256 instead perform the Wp plane-split (fused to save a launch).
// Output written as hi/lo PLANES.  Inner math unchanged (harness-verified).
// ---------------------------------------------------------------------------
#define KSTR 136
#define VSTR 40

__global__ __launch_bounds__(512) void attn_mfma_bf16(const unsigned short* __restrict__ qb,
                                                      const unsigned short* __restrict__ kb,
                                                      const unsigned short* __restrict__ vtb,
                                                      unsigned short* __restrict__ ofh,
                                                      const float4* __restrict__ wpsrc,
                                                      unsigned short* __restrict__ wps) {
  __shared__ unsigned short Kl[2][32 * KSTR];   // 2 x 8704 B
  __shared__ unsigned short Vl[2][128 * VSTR];  // 2 x 10240 B

  const int bid  = blockIdx.x;
  const int tid  = threadIdx.x;
  if (bid >= 256) {                       // fused Wp split: 2048 blocks x 512
    int k = (bid - 256) * 512 + tid;      // 1,048,576 float4 groups
    float4 f = wpsrc[k];
    float fv[4] = {f.x, f.y, f.z, f.w};
    ushort4 hv, lv;
#pragma unroll
    for (int e = 0; e < 4; ++e) {
      unsigned int u = __float_as_uint(fv[e]) & 0xffff0000u;
      ((unsigned short*)&hv)[e] = (unsigned short)(u >> 16);
      ((unsigned short*)&lv)[e] = f2bf(fv[e] - __uint_as_float(u));
    }
    *(ushort4*)(wps + 4 * (size_t)k)           = hv;
    *(ushort4*)(wps + 4194304 + 4 * (size_t)k) = lv;
    return;
  }

  const int tile = bid >> 2;              // 0..63 (32-row q-tiles)
  const int g    = bid & 3;
  const int t0b  = tile << 5;
  const int wv   = tid >> 6;
  const int hq   = wv & 3;
  const int sub  = wv >> 2;               // q-subtile within block
  const int h    = g * 4 + hq;
  const int lane = tid & 63;
  const int lo   = lane & 15;
  const int hi   = lane >> 4;
  const int t0w  = t0b + (sub << 4);
  const int t    = t0w + lo;              // this lane's q row

  // staging map: K: thread -> (local row sj, col sc); V: (d-row svd, col svj)
  const int sj   = tid >> 4;              // 0..31
  const int sc   = (tid & 15) << 3;       // 0,8,...,120
  const int kphi = ((((sj & 7) << 2) | (sj >> 3))) * KSTR + sc;
  const int svd  = tid >> 2;              // 0..127
  const int svj  = (tid & 3) << 3;        // 0,8,16,24
  const int vdst = svd * VSTR + svj;
  const unsigned short* ksrc = kb  + (size_t)sj * 512 + g * 128 + sc;
  const unsigned short* vsrc = vtb + (size_t)(g * 128 + svd) * JP + svj;

  // Q fragment (B operand of QK): lane holds q[t][d0*32 + 8*hi + e]
  short8 qfrag[4];
  {
    const unsigned short* qp = qb + (size_t)t * 2048 + h * 128 + (hi << 3);
#pragma unroll
    for (int d0 = 0; d0 < 4; ++d0) qfrag[d0] = *(const short8*)(qp + d0 * 32);
  }

  f32x4 acc[8];
  const f32x4 z4 = {0.f, 0.f, 0.f, 0.f};
#pragma unroll
  for (int dt = 0; dt < 8; ++dt) acc[dt] = z4;

  float m = -1e4f, l = 0.f;               // per-lane partial stats

  int jlo = t0b - 1022; if (jlo < 0) jlo = 0;
  const int jb0  = jlo & ~31;
  const int jmax = t0b + 32;              // largest valid j = (t0b+31)+1
  const int nch  = ((jmax - jb0) >> 5) + 1;

  // LDS fragment read offsets (K rows permuted: tile A -> phi in [0,16),
  // tile B (= row+4) -> phi+16)
  const int klA = (((lo & 3) << 2) | (lo >> 2)) * KSTR + (hi << 3);

  // prologue: stage chunk 0
  uint4 kreg = *(const uint4*)(ksrc + (size_t)jb0 * 512);
  uint4 vreg = *(const uint4*)(vsrc + jb0);
  *(uint4*)&Kl[0][kphi] = kreg;
  *(uint4*)&Vl[0][vdst] = vreg;
  __syncthreads();

  int bsel = 0;
  for (int ci = 0; ci < nch; ++ci) {
    const int jb = jb0 + (ci << 5);
    const bool more = (ci + 1 < nch);
    if (more) {                            // issue next-chunk loads early
      const int jn = jb + 32;
      kreg = *(const uint4*)(ksrc + (size_t)jn * 512);
      vreg = *(const uint4*)(vsrc + jn);
    }

    // ---- QK^T: two 16x16 S^T tiles over K=128 (4 d-chunks), from LDS
    const unsigned short* Kb = &Kl[bsel][0];
    f32x4 sa = z4, sb = z4;
#pragma unroll
    for (int d0 = 0; d0 < 4; ++d0) {
      short8 ka  = *(const short8*)(Kb + klA + d0 * 32);
      short8 kB2 = *(const short8*)(Kb + klA + 16 * KSTR + d0 * 32);
      sa = __builtin_amdgcn_mfma_f32_16x16x32_bf16(ka,  qfrag[d0], sa, 0, 0, 0);
      sb = __builtin_amdgcn_mfma_f32_16x16x32_bf16(kB2, qfrag[d0], sb, 0, 0, 0);
    }

    float z[8];
    const int jbase = jb + (hi << 3);
    const bool interior = (jb >= t0w - 1007) && (jb <= t0w - 30);
    if (interior) {
#pragma unroll
      for (int r = 0; r < 4; ++r) { z[r] = sa[r] * SL_F; z[r + 4] = sb[r] * SL_F; }
    } else {
#pragma unroll
      for (int r = 0; r < 8; ++r) {
        float sv = (r < 4) ? sa[r] : sb[r - 4];
        int j = jbase + r;
        bool valid = (j <= t + 1) && (j >= t - 1022);
        z[r] = valid ? sv * SL_F : -1e30f;
      }
    }

    float lmax = fmaxf(fmaxf(fmaxf(z[0], z[1]), fmaxf(z[2], z[3])),
                       fmaxf(fmaxf(z[4], z[5]), fmaxf(z[6], z[7])));
    if (!__all(lmax <= m + THR_L2)) {
      float cm = lmax;
      cm = fmaxf(cm, __shfl_xor(cm, 16, 64));
      cm = fmaxf(cm, __shfl_xor(cm, 32, 64));
      float mn = fmaxf(m, cm);
      float a  = exp2f(m - mn);
      l *= a;
#pragma unroll
      for (int dt = 0; dt < 8; ++dt) acc[dt] *= a;
      m = mn;
    }

    float p[8];
#pragma unroll
    for (int r = 0; r < 8; ++r) { p[r] = exp2f(z[r] - m); l += p[r]; }

    short8 pfrag;
#pragma unroll
    for (int e = 0; e < 8; ++e) pfrag[e] = (short)f2bf(p[e]);

    // ---- PV: O^T += V^T * P^T  (8 d-tiles of 16), from LDS
    const unsigned short* Vb = &Vl[bsel][0];
#pragma unroll
    for (int dt = 0; dt < 8; ++dt) {
      short8 vf = *(const short8*)(Vb + (dt * 16 + lo) * VSTR + (hi << 3));
      acc[dt] = __builtin_amdgcn_mfma_f32_16x16x32_bf16(vf, pfrag, acc[dt], 0, 0, 0);
    }

    if (more) {                            // write next chunk, flip buffers
      *(uint4*)&Kl[bsel ^ 1][kphi] = kreg;
      *(uint4*)&Vl[bsel ^ 1][vdst] = vreg;
      __syncthreads();
      bsel ^= 1;
    }
  }

  float lt = l;
  lt += __shfl_xor(lt, 16, 64);
  lt += __shfl_xor(lt, 32, 64);
  const float inv = 1.f / lt;

  // epilogue: write hi/lo PLANES (hi trunc / lo RNE)
  unsigned short* ofl = ofh + 4194304;
  const size_t elem = (size_t)t * 2048 + h * 128 + (hi << 2);
#pragma unroll
  for (int dt = 0; dt < 8; ++dt) {
    f32x4 o4 = acc[dt] * inv;
    ushort4 hv, lv;
#pragma unroll
    for (int e = 0; e < 4; ++e) {
      unsigned int u = __float_as_uint(o4[e]) & 0xffff0000u;
      ((unsigned short*)&hv)[e] = (unsigned short)(u >> 16);
      ((unsigned short*)&lv)[e] = f2bf(o4[e] - __uint_as_float(u));
    }
    *(ushort4*)(ofh + elem + dt * 16) = hv;
    *(ushort4*)(ofl + elem + dt * 16) = lv;
  }
}

extern "C" void kernel_launch(void* const* d_in, const int* in_sizes, int n_in,
                              void* d_out, int out_size, void* d_ws, size_t ws_size,
                              hipStream_t stream) {
  const float* x     = (const float*)d_in[0];   // (2048, 2048) f32
  const float* cosb  = (const float*)d_in[1];   // (2048, 64)   f32
  const float* sinb  = (const float*)d_in[2];   // (2048, 64)   f32
  const float* Wa    = (const float*)d_in[3];   // (3072, 2048) f32
  const float* Wp    = (const float*)d_in[4];   // (2048, 2048) f32
  const float* ksink = (const float*)d_in[5];   // (512,)       f32
  const float* vsink = (const float*)d_in[6];   // (512,)       f32
  float* y = (float*)d_out;                     // (2048, 2048) f32

  // Workspace aliasing plan (peak 67,108,864 B; stream-serial stages):
  //  [0,        25165824): qkv f32            (stages 2-3)
  //  [0,        16777216): wps (Wp planes)    (stage 4+; qkv dead after rope)
  //  [25165824, 50331648): was (Wa planes)    (stages 1-2)
  //  [25165824, 41943040): ofh/ofl (attn out) (stage 4+; was dead after GEMM1)
  //  [50331648, 67108864): xs  (x planes)     (stages 1-2)
  //  [50331648, 62980096): qb/kb/vtb          (stage 3+; xs dead after GEMM1)
  char* ws = (char*)d_ws;
  float*          qkv = (float*)ws;
  unsigned short* wps = (unsigned short*)ws;
  unsigned short* was = (unsigned short*)(ws + 25165824);
  unsigned short* ofh = (unsigned short*)(ws + 25165824);
  unsigned short* xs  = (unsigned short*)(ws + 50331648);
  unsigned short* qb  = (unsigned short*)(ws + 50331648);
  unsigned short* kbb = (unsigned short*)(ws + 58720256);
  unsigned short* vtb = (unsigned short*)(ws + 60850176);

  // 1. pre-split x and Wa into hi/lo planes
  split_pack<<<10240, 256, 0, stream>>>((const float4*)x, xs, 1048576, 4194304,
                                        (const float4*)Wa, was, 1572864, 6291456);
  // 2. qkv = x @ Wa^T  (plane-split MFMA, 128x128 tile, counted-vmcnt pipeline)
  gemm_sp<<<dim3(24, 16), 256, 0, stream>>>(xs, was, qkv, 2048, 3072, 2048);
  // 3. RoPE + operand assembly (coalesced; LDS-transposed V)
  rope2<<<RB_Q + RB_K + RB_KE + RB_V, 256, 0, stream>>>(qkv, cosb, sinb, ksink, vsink,
                                                        qb, kbb, vtb);
  // 4. MFMA flash attention (LDS-staged K/V, hi/lo-plane output) + fused Wp split
  attn_mfma_bf16<<<2304, 512, 0, stream>>>(qb, kbb, vtb, ofh, (const float4*)Wp, wps);
  // 5. y = o @ Wp^T
  gemm_sp<<<dim3(16, 16), 256, 0, stream>>>(ofh, wps, y, 2048, 2048, 2048);
}

// Round 10
// 282.152 us; speedup vs baseline: 1.2329x; 1.2329x over previous
//
#include <hip/hip_runtime.h>

#define T_SEQ  2048
#define JP     2080                       // padded key length (zeroed pads)
#define SL_F    0.12751744f               // SCALE * log2(e)
#define THR_L2  11.0f                     // defer-max threshold (log2 domain)

typedef __attribute__((ext_vector_type(8))) short short8;
typedef __attribute__((ext_vector_type(4))) float f32x4;
typedef __attribute__((ext_vector_type(4))) int   i32x4;

__device__ __forceinline__ unsigned short f2bf(float f) {
  unsigned int u = __float_as_uint(f);
  u += 0x7fff + ((u >> 16) & 1);          // round-to-nearest-even
  return (unsigned short)(u >> 16);
}

// async global->LDS 16B copy: LDS dest = wave-uniform base + lane*16
__device__ __forceinline__ void gload16(const void* g, void* l) {
  __builtin_amdgcn_global_load_lds(
      (const __attribute__((address_space(1))) void*)g,
      (__attribute__((address_space(3))) void*)l, 16, 0, 0);
}

// ---------------------------------------------------------------------------
// quant_rows: per-row int16 quantization -> two signed-i8 planes + f32 scale.
// Row value x ~= scale * (nh*256 + nl), |n| <= 32512 (127*256).  One block per
// row (2048 cols); block amax-reduce -> scale -> quantize.  Two sets/launch.
// ---------------------------------------------------------------------------
__global__ __launch_bounds__(256) void quant_rows(
    const float* __restrict__ s0, signed char* __restrict__ d0,
    float* __restrict__ sc0, int n0, int p0,
    const float* __restrict__ s1, signed char* __restrict__ d1,
    float* __restrict__ sc1, int n1, int p1) {
  __shared__ float red[4];
  int r = blockIdx.x;
  const float* s; signed char* d; float* sc; int p;
  if (r < n0) { s = s0; d = d0; sc = sc0; p = p0; }
  else { r -= n0; if (r >= n1) return; s = s1; d = d1; sc = sc1; p = p1; }
  const int tid = threadIdx.x;
  const float4* sp = (const float4*)(s + (size_t)r * 2048) + tid * 2;
  float4 v0 = sp[0], v1 = sp[1];
  float vv[8] = {v0.x, v0.y, v0.z, v0.w, v1.x, v1.y, v1.z, v1.w};
  float am = 0.f;
#pragma unroll
  for (int e = 0; e < 8; ++e) am = fmaxf(am, fabsf(vv[e]));
#pragma unroll
  for (int o = 1; o <= 32; o <<= 1) am = fmaxf(am, __shfl_xor(am, o, 64));
  if ((tid & 63) == 0) red[tid >> 6] = am;
  __syncthreads();
  am = fmaxf(fmaxf(red[0], red[1]), fmaxf(red[2], red[3]));
  const float inv = (am > 1e-30f) ? 32512.f / am : 0.f;
  if (tid == 0) sc[r] = am * (1.f / 32512.f);
  int hb[8], lb[8];
#pragma unroll
  for (int e = 0; e < 8; ++e) {
    int n  = __float2int_rn(vv[e] * inv);
    int nh = (n + 128) >> 8;              // nh in [-127,127]
    hb[e] = nh & 0xff;
    lb[e] = (n - (nh << 8)) & 0xff;       // nl in [-128,127]
  }
  int2 hw, lw;
  hw.x = hb[0] | (hb[1] << 8) | (hb[2] << 16) | (hb[3] << 24);
  hw.y = hb[4] | (hb[5] << 8) | (hb[6] << 16) | (hb[7] << 24);
  lw.x = lb[0] | (lb[1] << 8) | (lb[2] << 16) | (lb[3] << 24);
  lw.y = lb[4] | (lb[5] << 8) | (lb[6] << 16) | (lb[7] << 24);
  *(int2*)(d + (size_t)r * 2048 + tid * 8)     = hw;
  *(int2*)(d + p + (size_t)r * 2048 + tid * 8) = lw;
}

// ---------------------------------------------------------------------------
// Int8 3-pass MFMA GEMM: C[M,N] = A[M,K] * B[N,K]^T with per-row scales.
// C = sa[m]*sb[n] * (65536*acc_hh + 256*acc_cross); acc in exact i32;
// dropped nl*nl term ~1e-5 relative.  mfma_i32_16x16x64_i8: K=64/instr =
// 2x bf16 rate; LDS bytes and DMA bytes per unit work also halve.
// 128x128 tile, 4 waves, BK=64, double-buffered global_load_lds + counted
// vmcnt(8), linear LDS (64B rows -> b128 reads at the bank floor).
// ---------------------------------------------------------------------------
__global__ __launch_bounds__(256, 2) void gemm_i8(const signed char* __restrict__ Ag,
                                                  const signed char* __restrict__ Bg,
                                                  const float* __restrict__ sav,
                                                  const float* __restrict__ sbv,
                                                  float* __restrict__ C,
                                                  int M, int N, int K) {
  __shared__ signed char Anh[2][128 * 64], Anl[2][128 * 64];
  __shared__ signed char Bnh[2][128 * 64], Bnl[2][128 * 64];

  const int tid  = threadIdx.x;
  const int lane = tid & 63;
  const int wid  = tid >> 6;
  const int wm   = (wid >> 1) << 6;       // 0 / 64
  const int wn   = (wid & 1) << 6;        // 0 / 64
  const int lo16 = lane & 15;
  const int hi4  = lane >> 4;
  const int m0   = blockIdx.y << 7;
  const int n0   = blockIdx.x << 7;
  const size_t MK = (size_t)M * K;        // lo-plane offset (bytes == elems)
  const size_t NK = (size_t)N * K;

  // staging: per plane 512 x 16B chunks; wave w: rows w*16+(lane>>2) and +64
  const int r0 = (wid << 4) + (lane >> 2);
  const int r1 = r0 + 64;
  const int cB = (lane & 3) << 4;         // byte col within 64B row-chunk
  const signed char* a0g = Ag + (size_t)(m0 + r0) * K + cB;
  const signed char* a1g = Ag + (size_t)(m0 + r1) * K + cB;
  const signed char* b0g = Bg + (size_t)(n0 + r0) * K + cB;
  const signed char* b1g = Bg + (size_t)(n0 + r1) * K + cB;
  const int o0 = wid << 10;               // wave-uniform LDS byte offsets
  const int o1 = (4 + wid) << 10;

  // fragment reads: row = lane&15 (+16*i), k-bytes = (lane>>4)*16
  int ra[4], rb[4];
#pragma unroll
  for (int i = 0; i < 4; ++i) {
    ra[i] = ((wm + i * 16 + lo16) << 6) + (hi4 << 4);
    rb[i] = ((wn + i * 16 + lo16) << 6) + (hi4 << 4);
  }

  i32x4 acc1[4][4], acc2[4][4];
  const i32x4 zi = {0, 0, 0, 0};
#pragma unroll
  for (int i = 0; i < 4; ++i)
#pragma unroll
    for (int j = 0; j < 4; ++j) { acc1[i][j] = zi; acc2[i][j] = zi; }

  // prologue: stage K-step 0 into buffer 0 (8 DMA per wave)
  gload16(a0g,      &Anh[0][o0]);
  gload16(a1g,      &Anh[0][o1]);
  gload16(a0g + MK, &Anl[0][o0]);
  gload16(a1g + MK, &Anl[0][o1]);
  gload16(b0g,      &Bnh[0][o0]);
  gload16(b1g,      &Bnh[0][o1]);
  gload16(b0g + NK, &Bnl[0][o0]);
  gload16(b1g + NK, &Bnl[0][o1]);

  int cur = 0;
  for (int k0 = 0; k0 < K; k0 += 64) {
    const bool more = (k0 + 64) < K;
    if (more) {
      const int nxt = cur ^ 1;
      const int kn  = k0 + 64;
      gload16(a0g + kn,      &Anh[nxt][o0]);
      gload16(a1g + kn,      &Anh[nxt][o1]);
      gload16(a0g + MK + kn, &Anl[nxt][o0]);
      gload16(a1g + MK + kn, &Anl[nxt][o1]);
      gload16(b0g + kn,      &Bnh[nxt][o0]);
      gload16(b1g + kn,      &Bnh[nxt][o1]);
      gload16(b0g + NK + kn, &Bnl[nxt][o0]);
      gload16(b1g + NK + kn, &Bnl[nxt][o1]);
      asm volatile("s_waitcnt vmcnt(8)" ::: "memory");
    } else {
      asm volatile("s_waitcnt vmcnt(0)" ::: "memory");
    }
    __builtin_amdgcn_s_barrier();
    __builtin_amdgcn_sched_barrier(0);

    i32x4 fah[4], fal[4], fbh[4], fbl[4];
#pragma unroll
    for (int i = 0; i < 4; ++i) {
      fah[i] = *(const i32x4*)&Anh[cur][ra[i]];
      fal[i] = *(const i32x4*)&Anl[cur][ra[i]];
      fbh[i] = *(const i32x4*)&Bnh[cur][rb[i]];
      fbl[i] = *(const i32x4*)&Bnl[cur][rb[i]];
    }
#pragma unroll
    for (int i = 0; i < 4; ++i)
#pragma unroll
      for (int j = 0; j < 4; ++j) {
        acc1[i][j] = __builtin_amdgcn_mfma_i32_16x16x64_i8(fah[i], fbh[j], acc1[i][j], 0, 0, 0);
        acc2[i][j] = __builtin_amdgcn_mfma_i32_16x16x64_i8(fah[i], fbl[j], acc2[i][j], 0, 0, 0);
        acc2[i][j] = __builtin_amdgcn_mfma_i32_16x16x64_i8(fal[i], fbh[j], acc2[i][j], 0, 0, 0);
      }

    __builtin_amdgcn_sched_barrier(0);
    __builtin_amdgcn_s_barrier();
    asm volatile("" ::: "memory");
    cur ^= 1;
  }

  // epilogue: D col = lane&15, row = (lane>>4)*4 + reg; dequant with scales
#pragma unroll
  for (int i = 0; i < 4; ++i) {
    const int rowb = m0 + wm + i * 16 + (hi4 << 2);
    float sa0 = sav[rowb], sa1 = sav[rowb + 1], sa2 = sav[rowb + 2], sa3 = sav[rowb + 3];
#pragma unroll
    for (int j = 0; j < 4; ++j) {
      const int col = n0 + wn + j * 16 + lo16;
      const float sb = sbv[col];
      float* cp = C + (size_t)rowb * N + col;
      cp[0]           = fmaf(65536.f, (float)acc1[i][j][0], 256.f * (float)acc2[i][j][0]) * sa0 * sb;
      cp[(size_t)N]   = fmaf(65536.f, (float)acc1[i][j][1], 256.f * (float)acc2[i][j][1]) * sa1 * sb;
      cp[(size_t)2*N] = fmaf(65536.f, (float)acc1[i][j][2], 256.f * (float)acc2[i][j][2]) * sa2 * sb;
      cp[(size_t)3*N] = fmaf(65536.f, (float)acc1[i][j][3], 256.f * (float)acc2[i][j][3]) * sa3 * sb;
    }
  }
}

// ---------------------------------------------------------------------------
// rope2: RoPE + bf16 operand assembly, all sections coalesced.  (unchanged)
// ---------------------------------------------------------------------------
#define RB_Q  4096
#define RB_K  1024
#define RB_KE 64
#define RB_V  65

__global__ __launch_bounds__(256) void rope2(const float* __restrict__ qkv,
                                             const float* __restrict__ cosb,
                                             const float* __restrict__ sinb,
                                             const float* __restrict__ ksink,
                                             const float* __restrict__ vsink,
                                             unsigned short* __restrict__ qb,
                                             unsigned short* __restrict__ kb,
                                             unsigned short* __restrict__ vtb) {
  __shared__ unsigned short tl[512 * 33];
  const int bid = blockIdx.x, tid = threadIdx.x;
  if (bid < RB_Q) {
    int idx = bid * 256 + tid;            // 1,048,576: (t, h, dp/2)
    int t = idx >> 9, rem = idx & 511;
    int h = rem >> 5, dp = (rem & 31) << 1;
    int g = h >> 2, qi = h & 3;
    const float* src = qkv + (size_t)t * 3072 + g * 768 + qi * 128;
    float2 x1 = *(const float2*)(src + dp);
    float2 x2 = *(const float2*)(src + 64 + dp);
    float2 c  = *(const float2*)(cosb + t * 64 + dp);
    float2 s  = *(const float2*)(sinb + t * 64 + dp);
    ushort2 o1 = { f2bf(x1.x * c.x - x2.x * s.x), f2bf(x1.y * c.y - x2.y * s.y) };
    ushort2 o2 = { f2bf(x1.x * s.x + x2.x * c.x), f2bf(x1.y * s.y + x2.y * c.y) };
    *(ushort2*)(qb + (size_t)t * 2048 + h * 128 + dp)      = o1;
    *(ushort2*)(qb + (size_t)t * 2048 + h * 128 + 64 + dp) = o2;
  } else if (bid < RB_Q + RB_K) {
    int idx = (bid - RB_Q) * 256 + tid;   // 262,144: (t, g, dp/2)
    int t = idx >> 7, rem = idx & 127;
    int g = rem >> 5, dp = (rem & 31) << 1;
    const float* src = qkv + (size_t)t * 3072 + g * 768 + 512;
    float2 x1 = *(const float2*)(src + dp);
    float2 x2 = *(const float2*)(src + 64 + dp);
    float2 c  = *(const float2*)(cosb + t * 64 + dp);
    float2 s  = *(const float2*)(sinb + t * 64 + dp);
    ushort2 o1 = { f2bf(x1.x * c.x - x2.x * s.x), f2bf(x1.y * c.y - x2.y * s.y) };
    ushort2 o2 = { f2bf(x1.x * s.x + x2.x * c.x), f2bf(x1.y * s.y + x2.y * c.y) };
    size_t base = (size_t)(t + 1) * 512 + g * 128 + dp;
    *(ushort2*)(kb + base)      = o1;
    *(ushort2*)(kb + base + 64) = o2;
  } else if (bid < RB_Q + RB_K + RB_KE) {
    int idx = (bid - RB_Q - RB_K) * 256 + tid;   // 16,384: sink + pads
    int jj = idx >> 9, c = idx & 511;
    if (jj == 0) kb[c] = f2bf(ksink[c]);
    else         kb[(size_t)(2048 + jj) * 512 + c] = 0;
  } else {
    int b  = bid - RB_Q - RB_K - RB_KE;   // 0..64, j-tile of 32
    int j0 = b << 5;
#pragma unroll 4
    for (int st = 0; st < 64; ++st) {
      int id = st * 256 + tid;            // 16,384 = 32 j x 512 gd
      int jj = id >> 9, c = id & 511;
      int j = j0 + jj;
      float val;
      if (j == 0)          val = vsink[c];
      else if (j <= T_SEQ) val = qkv[(size_t)(j - 1) * 3072 + (c >> 7) * 768 + 640 + (c & 127)];
      else                 val = 0.f;
      tl[c * 33 + jj] = f2bf(val);
    }
    __syncthreads();
#pragma unroll 4
    for (int st = 0; st < 32; ++st) {
      int id = st * 256 + tid;            // 8,192 = 512 rows x 16 jp-pairs
      int row = id >> 4, jp = (id & 15) << 1;
      ushort2 w = { tl[row * 33 + jp], tl[row * 33 + jp + 1] };
      *(ushort2*)(vtb + (size_t)row * JP + j0 + jp) = w;
    }
  }
}

// ---------------------------------------------------------------------------
// MFMA flash attention with per-block LDS K/V staging (double-buffered).
// Output: plain f32 (quantized for GEMM2 by quant_rows).  Inner math
// unchanged (harness-verified).
// ---------------------------------------------------------------------------
#define KSTR 136
#define VSTR 40

__global__ __launch_bounds__(512) void attn_mfma_bf16(const unsigned short* __restrict__ qb,
                                                      const unsigned short* __restrict__ kb,
                                                      const unsigned short* __restrict__ vtb,
                                                      float* __restrict__ of) {
  __shared__ unsigned short Kl[2][32 * KSTR];   // 2 x 8704 B
  __shared__ unsigned short Vl[2][128 * VSTR];  // 2 x 10240 B

  const int bid  = blockIdx.x;
  const int tid  = threadIdx.x;
  const int tile = bid >> 2;              // 0..63 (32-row q-tiles)
  const int g    = bid & 3;
  const int t0b  = tile << 5;
  const int wv   = tid >> 6;
  const int hq   = wv & 3;
  const int sub  = wv >> 2;               // q-subtile within block
  const int h    = g * 4 + hq;
  const int lane = tid & 63;
  const int lo   = lane & 15;
  const int hi   = lane >> 4;
  const int t0w  = t0b + (sub << 4);
  const int t    = t0w + lo;              // this lane's q row

  // staging map: K: thread -> (local row sj, col sc); V: (d-row svd, col svj)
  const int sj   = tid >> 4;              // 0..31
  const int sc   = (tid & 15) << 3;       // 0,8,...,120
  const int kphi = ((((sj & 7) << 2) | (sj >> 3))) * KSTR + sc;
  const int svd  = tid >> 2;              // 0..127
  const int svj  = (tid & 3) << 3;        // 0,8,16,24
  const int vdst = svd * VSTR + svj;
  const unsigned short* ksrc = kb  + (size_t)sj * 512 + g * 128 + sc;
  const unsigned short* vsrc = vtb + (size_t)(g * 128 + svd) * JP + svj;

  // Q fragment (B operand of QK): lane holds q[t][d0*32 + 8*hi + e]
  short8 qfrag[4];
  {
    const unsigned short* qp = qb + (size_t)t * 2048 + h * 128 + (hi << 3);
#pragma unroll
    for (int d0 = 0; d0 < 4; ++d0) qfrag[d0] = *(const short8*)(qp + d0 * 32);
  }

  f32x4 acc[8];
  const f32x4 z4 = {0.f, 0.f, 0.f, 0.f};
#pragma unroll
  for (int dt = 0; dt < 8; ++dt) acc[dt] = z4;

  float m = -1e4f, l = 0.f;               // per-lane partial stats

  int jlo = t0b - 1022; if (jlo < 0) jlo = 0;
  const int jb0  = jlo & ~31;
  const int jmax = t0b + 32;              // largest valid j = (t0b+31)+1
  const int nch  = ((jmax - jb0) >> 5) + 1;

  const int klA = (((lo & 3) << 2) | (lo >> 2)) * KSTR + (hi << 3);

  // prologue: stage chunk 0
  uint4 kreg = *(const uint4*)(ksrc + (size_t)jb0 * 512);
  uint4 vreg = *(const uint4*)(vsrc + jb0);
  *(uint4*)&Kl[0][kphi] = kreg;
  *(uint4*)&Vl[0][vdst] = vreg;
  __syncthreads();

  int bsel = 0;
  for (int ci = 0; ci < nch; ++ci) {
    const int jb = jb0 + (ci << 5);
    const bool more = (ci + 1 < nch);
    if (more) {                            // issue next-chunk loads early
      const int jn = jb + 32;
      kreg = *(const uint4*)(ksrc + (size_t)jn * 512);
      vreg = *(const uint4*)(vsrc + jn);
    }

    // ---- QK^T: two 16x16 S^T tiles over K=128 (4 d-chunks), from LDS
    const unsigned short* Kb = &Kl[bsel][0];
    f32x4 sa = z4, sb = z4;
#pragma unroll
    for (int d0 = 0; d0 < 4; ++d0) {
      short8 ka  = *(const short8*)(Kb + klA + d0 * 32);
      short8 kB2 = *(const short8*)(Kb + klA + 16 * KSTR + d0 * 32);
      sa = __builtin_amdgcn_mfma_f32_16x16x32_bf16(ka,  qfrag[d0], sa, 0, 0, 0);
      sb = __builtin_amdgcn_mfma_f32_16x16x32_bf16(kB2, qfrag[d0], sb, 0, 0, 0);
    }

    float z[8];
    const int jbase = jb + (hi << 3);
    const bool interior = (jb >= t0w - 1007) && (jb <= t0w - 30);
    if (interior) {
#pragma unroll
      for (int r = 0; r < 4; ++r) { z[r] = sa[r] * SL_F; z[r + 4] = sb[r] * SL_F; }
    } else {
#pragma unroll
      for (int r = 0; r < 8; ++r) {
        float sv = (r < 4) ? sa[r] : sb[r - 4];
        int j = jbase + r;
        bool valid = (j <= t + 1) && (j >= t - 1022);
        z[r] = valid ? sv * SL_F : -1e30f;
      }
    }

    float lmax = fmaxf(fmaxf(fmaxf(z[0], z[1]), fmaxf(z[2], z[3])),
                       fmaxf(fmaxf(z[4], z[5]), fmaxf(z[6], z[7])));
    if (!__all(lmax <= m + THR_L2)) {
      float cm = lmax;
      cm = fmaxf(cm, __shfl_xor(cm, 16, 64));
      cm = fmaxf(cm, __shfl_xor(cm, 32, 64));
      float mn = fmaxf(m, cm);
      float a  = exp2f(m - mn);
      l *= a;
#pragma unroll
      for (int dt = 0; dt < 8; ++dt) acc[dt] *= a;
      m = mn;
    }

    float p[8];
#pragma unroll
    for (int r = 0; r < 8; ++r) { p[r] = exp2f(z[r] - m); l += p[r]; }

    short8 pfrag;
#pragma unroll
    for (int e = 0; e < 8; ++e) pfrag[e] = (short)f2bf(p[e]);

    // ---- PV: O^T += V^T * P^T  (8 d-tiles of 16), from LDS
    const unsigned short* Vb = &Vl[bsel][0];
#pragma unroll
    for (int dt = 0; dt < 8; ++dt) {
      short8 vf = *(const short8*)(Vb + (dt * 16 + lo) * VSTR + (hi << 3));
      acc[dt] = __builtin_amdgcn_mfma_f32_16x16x32_bf16(vf, pfrag, acc[dt], 0, 0, 0);
    }

    if (more) {                            // write next chunk, flip buffers
      *(uint4*)&Kl[bsel ^ 1][kphi] = kreg;
      *(uint4*)&Vl[bsel ^ 1][vdst] = vreg;
      __syncthreads();
      bsel ^= 1;
    }
  }

  float lt = l;
  lt += __shfl_xor(lt, 16, 64);
  lt += __shfl_xor(lt, 32, 64);
  const float inv = 1.f / lt;

  // epilogue: plain f32 O^T writes (R1-verified mapping)
  float* op = of + (size_t)t * 2048 + h * 128 + (hi << 2);
#pragma unroll
  for (int dt = 0; dt < 8; ++dt) {
    f32x4 o4 = acc[dt] * inv;
    *(f32x4*)(op + dt * 16) = o4;
  }
}

extern "C" void kernel_launch(void* const* d_in, const int* in_sizes, int n_in,
                              void* d_out, int out_size, void* d_ws, size_t ws_size,
                              hipStream_t stream) {
  const float* x     = (const float*)d_in[0];   // (2048, 2048) f32
  const float* cosb  = (const float*)d_in[1];   // (2048, 64)   f32
  const float* sinb  = (const float*)d_in[2];   // (2048, 64)   f32
  const float* Wa    = (const float*)d_in[3];   // (3072, 2048) f32
  const float* Wp    = (const float*)d_in[4];   // (2048, 2048) f32
  const float* ksink = (const float*)d_in[5];   // (512,)       f32
  const float* vsink = (const float*)d_in[6];   // (512,)       f32
  float* y = (float*)d_out;                     // (2048, 2048) f32

  // Workspace (peak ~51.4 MB; stream-serial stages):
  //  [0,        25165824): qkv f32 (st2-3) | of f32 [0,16.8M) + o planes
  //                        [16777216,25165824) (st5-7)
  //  [25165824, 38748736): Wa planes (st1-2) | Wp planes [25.2M,+8.4M) (st4+)
  //  [38748736, 47137344): x planes (st1-2)  | qb (st3+)
  //  [47137344, 49267264): kb
  //  [49267264, 51397184): vtb
  //  [51397184, +): scales s_x, s_wa, s_wp, s_o
  char* ws = (char*)d_ws;
  float*          qkv = (float*)ws;
  float*          of  = (float*)ws;
  signed char*    ops = (signed char*)(ws + 16777216);
  signed char*    was = (signed char*)(ws + 25165824);
  signed char*    wps = (signed char*)(ws + 25165824);
  signed char*    xs  = (signed char*)(ws + 38748736);
  unsigned short* qb  = (unsigned short*)(ws + 38748736);
  unsigned short* kbb = (unsigned short*)(ws + 47137344);
  unsigned short* vtb = (unsigned short*)(ws + 49267264);
  float*          s_x  = (float*)(ws + 51397184);
  float*          s_wa = (float*)(ws + 51405376);
  float*          s_wp = (float*)(ws + 51417664);
  float*          s_o  = (float*)(ws + 51425856);

  // 1. quantize x and Wa (per-row int16 -> i8 planes + scales)
  quant_rows<<<5120, 256, 0, stream>>>(x, xs, s_x, 2048, 4194304,
                                       Wa, was, s_wa, 3072, 6291456);
  // 2. qkv = x @ Wa^T  (int8 3-pass MFMA)
  gemm_i8<<<dim3(24, 16), 256, 0, stream>>>(xs, was, s_x, s_wa, qkv, 2048, 3072, 2048);
  // 3. RoPE + operand assembly (coalesced; LDS-transposed V)
  rope2<<<RB_Q + RB_K + RB_KE + RB_V, 256, 0, stream>>>(qkv, cosb, sinb, ksink, vsink,
                                                        qb, kbb, vtb);
  // 4. quantize Wp (into dead Wa-plane region)
  quant_rows<<<2048, 256, 0, stream>>>(Wp, wps, s_wp, 2048, 4194304,
                                       Wp, wps, s_wp, 0, 0);
  // 5. MFMA flash attention (LDS-staged K/V, f32 output)
  attn_mfma_bf16<<<256, 512, 0, stream>>>(qb, kbb, vtb, of);
  // 6. quantize o
  quant_rows<<<2048, 256, 0, stream>>>(of, ops, s_o, 2048, 4194304,
                                       of, ops, s_o, 0, 0);
  // 7. y = o @ Wp^T  (int8 3-pass MFMA)
  gemm_i8<<<dim3(16, 16), 256, 0, stream>>>(ops, wps, s_o, s_wp, y, 2048, 2048, 2048);
}